// Round 1
// baseline (489.193 us; speedup 1.0000x reference)
//
#include <hip/hip_runtime.h>
#include <hip/hip_bf16.h>

typedef unsigned short u16;
typedef __attribute__((ext_vector_type(8)))  __bf16 bf16x8;
typedef __attribute__((ext_vector_type(8)))  unsigned short u16x8;
typedef __attribute__((ext_vector_type(4)))  unsigned short u16x4;
typedef __attribute__((ext_vector_type(4)))  float f32x4;

#define MFMA(a, b, c) __builtin_amdgcn_mfma_f32_16x16x32_bf16((a), (b), (c), 0, 0, 0)

// f32 -> bf16 round-to-nearest-even (bit trick)
__device__ __forceinline__ u16 f2b(float f) {
  union { float f; unsigned u; } x; x.f = f;
  unsigned r = x.u + 0x7fffu + ((x.u >> 16) & 1u);
  return (u16)(r >> 16);
}

__device__ __forceinline__ void gl_lds16(void* lds, const void* g) {
  __builtin_amdgcn_global_load_lds(
      (const __attribute__((address_space(1))) void*)g,
      (__attribute__((address_space(3))) void*)lds, 16, 0, 0);
}

// ---------------- f32 -> bf16 elementwise ----------------
__global__ __launch_bounds__(256) void cvt_kernel(const float* __restrict__ in,
                                                  u16* __restrict__ out, int n) {
  int i = (blockIdx.x * 256 + threadIdx.x) * 4;
  if (i >= n) return;
  f32x4 v = *(const f32x4*)(in + i);
  u16x4 o;
  o[0] = f2b(v[0]); o[1] = f2b(v[1]); o[2] = f2b(v[2]); o[3] = f2b(v[3]);
  *(u16x4*)(out + i) = o;
}

// ---------------- f32 [K][N] -> bf16 [N][K] transpose ----------------
__global__ __launch_bounds__(256) void cvt_t_kernel(const float* __restrict__ W,
                                                    u16* __restrict__ Wt, int K, int N) {
  __shared__ u16 t[32][33];
  const int n0 = blockIdx.x * 32, k0 = blockIdx.y * 32;
  const int tc = threadIdx.x & 31, tr = threadIdx.x >> 5; // tr: 0..7
#pragma unroll
  for (int i = 0; i < 4; i++)
    t[tr + i * 8][tc] = f2b(W[(size_t)(k0 + tr + i * 8) * N + n0 + tc]);
  __syncthreads();
#pragma unroll
  for (int i = 0; i < 4; i++)
    Wt[(size_t)(n0 + tr + i * 8) * K + k0 + tc] = t[tc][tr + i * 8];
}

// ---------------- shared GEMM body: C[M=4096][N] = A[4096][2048] @ Bt[N][2048]^T + bias ----------------
// A, Bt bf16 row-major (both K-contiguous). 128x128 tile, BK=32, 4 waves (2x2 of 64x64).
template <bool OUT_BF16>
__device__ __forceinline__ void gemm_body(const u16* __restrict__ A, const u16* __restrict__ Bt,
                                          const float* __restrict__ bias, void* __restrict__ C,
                                          const int N, const int n0, const int m0, const float scale) {
  __shared__ __align__(16) u16 As[128 * 32];
  __shared__ __align__(16) u16 Bs[128 * 32];
  const int lane = threadIdx.x & 63, wv = threadIdx.x >> 6;
  const int l15 = lane & 15, lg = lane >> 4;
  const int wm = wv >> 1, wn = wv & 1;
  const int rowQ = lane >> 2;   // 0..15 within a 16-row chunk (4 lanes of 16B per 64B row)
  const int g = lane & 3;       // 8-elem group within row

  f32x4 acc[4][4] = {};

  for (int k0 = 0; k0 < 2048; k0 += 32) {
    // stage A-tile [128][32] and B-tile [128][32]; XOR-swizzled source so the
    // swizzled fragment read below is conflict-reduced (linear LDS dest, rule #21)
#pragma unroll
    for (int c = 0; c < 2; c++) {
      const int cc = c * 4 + wv;          // 8 chunks of 16 rows
      const int row = cc * 16 + rowQ;
      const int gs = g ^ ((row >> 1) & 3);
      gl_lds16(&As[cc * 512], A + (((size_t)(m0 + row)) << 11) + k0 + gs * 8);
      gl_lds16(&Bs[cc * 512], Bt + (((size_t)(n0 + row)) << 11) + k0 + gs * 8);
    }
    __syncthreads();
    bf16x8 af[4], bfr[4];
#pragma unroll
    for (int t = 0; t < 4; t++) {
      const int ra = wm * 64 + t * 16 + l15;
      af[t] = *(const bf16x8*)&As[ra * 32 + ((lg ^ ((ra >> 1) & 3)) << 3)];
      const int rb = wn * 64 + t * 16 + l15;
      bfr[t] = *(const bf16x8*)&Bs[rb * 32 + ((lg ^ ((rb >> 1) & 3)) << 3)];
    }
#pragma unroll
    for (int mt = 0; mt < 4; mt++)
#pragma unroll
      for (int nt = 0; nt < 4; nt++)
        acc[mt][nt] = MFMA(af[mt], bfr[nt], acc[mt][nt]);
    __syncthreads();
  }

#pragma unroll
  for (int nt = 0; nt < 4; nt++) {
    const int col = n0 + wn * 64 + nt * 16 + l15;
    const float bc = bias[col];
#pragma unroll
    for (int mt = 0; mt < 4; mt++) {
#pragma unroll
      for (int r = 0; r < 4; r++) {
        const int row = m0 + wm * 64 + mt * 16 + lg * 4 + r;
        const float v = (acc[mt][nt][r] + bc) * scale;
        if (OUT_BF16) ((u16*)C)[(size_t)row * N + col] = f2b(v);
        else          ((float*)C)[(size_t)row * N + col] = v;
      }
    }
  }
}

// Fused QKV projection: grid.x = 16 (Q) + 4 (K) + 4 (V) column-blocks, grid.y = 32 row-blocks
__global__ __launch_bounds__(256) void qkv_gemm_kernel(
    const u16* __restrict__ xb,
    const u16* __restrict__ Wqt, const u16* __restrict__ Wkt, const u16* __restrict__ Wvt,
    const float* __restrict__ bq, const float* __restrict__ bk, const float* __restrict__ bv,
    u16* __restrict__ Qb, u16* __restrict__ Kb, u16* __restrict__ Vb) {
  const int nb = blockIdx.x;
  const u16* Bt; const float* bias; u16* out; int N, n0; float scale;
  if (nb < 16)      { Bt = Wqt; bias = bq; out = Qb; N = 2048; n0 = nb * 128;        scale = 0.125f; }
  else if (nb < 20) { Bt = Wkt; bias = bk; out = Kb; N = 512;  n0 = (nb - 16) * 128; scale = 1.0f; }
  else              { Bt = Wvt; bias = bv; out = Vb; N = 512;  n0 = (nb - 20) * 128; scale = 1.0f; }
  gemm_body<true>(xb, Bt, bias, out, N, n0, blockIdx.y * 128, scale);
}

__global__ __launch_bounds__(256) void oproj_kernel(const u16* __restrict__ Ab,
                                                    const u16* __restrict__ Wot,
                                                    const float* __restrict__ bo,
                                                    float* __restrict__ out) {
  gemm_body<false>(Ab, Wot, bo, out, 2048, blockIdx.x * 128, blockIdx.y * 128, 1.0f);
}

// ---------------- causal GQA flash attention ----------------
// grid = (T/64, Hq, B); block = 256 (4 waves x 16 q-rows). Scores pre-scaled via Q.
__global__ __launch_bounds__(256) void attn_kernel(const u16* __restrict__ Qb,
                                                   const u16* __restrict__ Kb,
                                                   const u16* __restrict__ Vb,
                                                   u16* __restrict__ Ab) {
  const int qt = blockIdx.x, h = blockIdx.y, b = blockIdx.z;
  const int kh = h >> 2;
  const int lane = threadIdx.x & 63, wv = threadIdx.x >> 6;
  const int l15 = lane & 15, lg = lane >> 4;

  __shared__ __align__(16) u16 Ks[64 * 72];       // [kv][d], padded
  __shared__ __align__(16) u16 Vt[64 * 72];       // [d][kv], padded
  __shared__ __align__(16) u16 Ps[4 * 16 * 72];   // per-wave P [16 q][64 kv], padded

  const int q0 = qt * 64;
  // Q fragments (A-operand): row = l15, k (=d) contiguous
  bf16x8 qf[2];
  {
    const u16* qp = Qb + (size_t)(b * 2048 + q0 + wv * 16 + l15) * 2048 + h * 64 + lg * 8;
    qf[0] = *(const bf16x8*)qp;
    qf[1] = *(const bf16x8*)(qp + 32);
  }
  f32x4 o[4] = {};
  float mrow[4] = {-1e30f, -1e30f, -1e30f, -1e30f};
  float srow[4] = {0.f, 0.f, 0.f, 0.f};
  u16* Pw = &Ps[wv * 16 * 72];

  for (int it = 0; it <= qt; it++) {
    const int kv0 = it * 64;
    __syncthreads();  // protect Ks/Vt against previous iteration's readers
    // stage K tile [64 kv][64 d]
#pragma unroll
    for (int s = 0; s < 2; s++) {
      const int ii = threadIdx.x + s * 256;
      const int row = ii >> 3, c = ii & 7;
      u16x8 kv = *(const u16x8*)(Kb + (size_t)(b * 2048 + kv0 + row) * 512 + kh * 64 + c * 8);
      *(u16x8*)&Ks[row * 72 + c * 8] = kv;
    }
    // stage V tile transposed: Vt[d][kv]
#pragma unroll
    for (int s = 0; s < 2; s++) {
      const int ii = threadIdx.x + s * 256;
      const int kv = ii >> 3, d0 = (ii & 7) * 8;
      u16x8 vv = *(const u16x8*)(Vb + (size_t)(b * 2048 + kv0 + kv) * 512 + kh * 64 + d0);
#pragma unroll
      for (int j = 0; j < 8; j++) Vt[(d0 + j) * 72 + kv] = vv[j];
    }
    __syncthreads();

    // S = Q K^T : D col = kv (l15 within 16-tile), D row = q (lg*4+r)
    f32x4 sc[4] = {};
#pragma unroll
    for (int kt = 0; kt < 4; kt++) {
#pragma unroll
      for (int ks = 0; ks < 2; ks++) {
        bf16x8 kf = *(const bf16x8*)&Ks[(kt * 16 + l15) * 72 + ks * 32 + lg * 8];
        sc[kt] = MFMA(qf[ks], kf, sc[kt]);
      }
    }
    // causal mask (diagonal tile only)
    if (it == qt) {
#pragma unroll
      for (int kt = 0; kt < 4; kt++)
#pragma unroll
        for (int r = 0; r < 4; r++) {
          const int q = q0 + wv * 16 + lg * 4 + r;
          const int kv = kv0 + kt * 16 + l15;
          if (kv > q) sc[kt][r] = -1e30f;
        }
    }
    // row max over kv (4 regs + 16-lane shuffle tree)
    float tmax[4];
#pragma unroll
    for (int r = 0; r < 4; r++)
      tmax[r] = fmaxf(fmaxf(sc[0][r], sc[1][r]), fmaxf(sc[2][r], sc[3][r]));
#pragma unroll
    for (int m = 1; m < 16; m <<= 1)
#pragma unroll
      for (int r = 0; r < 4; r++)
        tmax[r] = fmaxf(tmax[r], __shfl_xor(tmax[r], m));

    float scl[4];
#pragma unroll
    for (int r = 0; r < 4; r++) {
      const float mnew = fmaxf(mrow[r], tmax[r]);
      scl[r] = __expf(mrow[r] - mnew);
      mrow[r] = mnew;
    }
    float psum[4] = {0.f, 0.f, 0.f, 0.f};
#pragma unroll
    for (int kt = 0; kt < 4; kt++)
#pragma unroll
      for (int r = 0; r < 4; r++) {
        const float p = __expf(sc[kt][r] - mrow[r]);
        psum[r] += p;
        Pw[(lg * 4 + r) * 72 + kt * 16 + l15] = f2b(p);
      }
#pragma unroll
    for (int m = 1; m < 16; m <<= 1)
#pragma unroll
      for (int r = 0; r < 4; r++)
        psum[r] += __shfl_xor(psum[r], m);
#pragma unroll
    for (int r = 0; r < 4; r++)
      srow[r] = srow[r] * scl[r] + psum[r];
#pragma unroll
    for (int dt = 0; dt < 4; dt++)
#pragma unroll
      for (int r = 0; r < 4; r++)
        o[dt][r] *= scl[r];

    // O += P V  (P from per-wave LDS; same-wave DS ordering is in-order)
#pragma unroll
    for (int ks = 0; ks < 2; ks++) {
      bf16x8 pf = *(const bf16x8*)&Pw[l15 * 72 + ks * 32 + lg * 8];
#pragma unroll
      for (int dt = 0; dt < 4; dt++) {
        bf16x8 vf = *(const bf16x8*)&Vt[(dt * 16 + l15) * 72 + ks * 32 + lg * 8];
        o[dt] = MFMA(pf, vf, o[dt]);
      }
    }
  }

#pragma unroll
  for (int dt = 0; dt < 4; dt++)
#pragma unroll
    for (int r = 0; r < 4; r++) {
      const int q = q0 + wv * 16 + lg * 4 + r;
      Ab[(size_t)(b * 2048 + q) * 2048 + h * 64 + dt * 16 + l15] = f2b(o[dt][r] / srow[r]);
    }
}

extern "C" void kernel_launch(void* const* d_in, const int* in_sizes, int n_in,
                              void* d_out, int out_size, void* d_ws, size_t ws_size,
                              hipStream_t stream) {
  const float* x  = (const float*)d_in[0];
  const float* Wq = (const float*)d_in[1];
  const float* bq = (const float*)d_in[2];
  const float* Wk = (const float*)d_in[3];
  const float* bk = (const float*)d_in[4];
  const float* Wv = (const float*)d_in[5];
  const float* bv = (const float*)d_in[6];
  const float* Wo = (const float*)d_in[7];
  const float* bo = (const float*)d_in[8];

  char* ws = (char*)d_ws;
  // xb dead after QKV gemm; Ab aliases it.
  u16* xb  = (u16*)(ws + 0);          // 4096*2048 bf16 = 16 MiB
  u16* Ab  = (u16*)(ws + 0);          // aliases xb
  u16* Qb  = (u16*)(ws + 16777216);   // 4096*2048
  u16* Kb  = (u16*)(ws + 33554432);   // 4096*512
  u16* Vb  = (u16*)(ws + 37748736);   // 4096*512
  u16* Wqt = (u16*)(ws + 41943040);   // 2048*2048
  u16* Wkt = (u16*)(ws + 50331648);   // 512*2048
  u16* Wvt = (u16*)(ws + 52428800);   // 512*2048
  u16* Wot = (u16*)(ws + 54525952);   // 2048*2048  (end: 62,914,560 bytes)

  cvt_kernel<<<8192, 256, 0, stream>>>(x, xb, 2 * 2048 * 2048);
  cvt_t_kernel<<<dim3(64, 64), 256, 0, stream>>>(Wq, Wqt, 2048, 2048);
  cvt_t_kernel<<<dim3(16, 64), 256, 0, stream>>>(Wk, Wkt, 2048, 512);
  cvt_t_kernel<<<dim3(16, 64), 256, 0, stream>>>(Wv, Wvt, 2048, 512);
  cvt_t_kernel<<<dim3(64, 64), 256, 0, stream>>>(Wo, Wot, 2048, 2048);

  qkv_gemm_kernel<<<dim3(24, 32), 256, 0, stream>>>(xb, Wqt, Wkt, Wvt, bq, bk, bv, Qb, Kb, Vb);
  attn_kernel<<<dim3(32, 32, 2), 256, 0, stream>>>(Qb, Kb, Vb, Ab);
  oproj_kernel<<<dim3(16, 32), 256, 0, stream>>>(Ab, Wot, bo, (float*)d_out);
}

// Round 2
// 305.814 us; speedup vs baseline: 1.5996x; 1.5996x over previous
//
#include <hip/hip_runtime.h>
#include <hip/hip_bf16.h>

typedef unsigned short u16;
typedef __attribute__((ext_vector_type(8)))  __bf16 bf16x8;
typedef __attribute__((ext_vector_type(8)))  unsigned short u16x8;
typedef __attribute__((ext_vector_type(4)))  unsigned short u16x4;
typedef __attribute__((ext_vector_type(4)))  float f32x4;

#define MFMA(a, b, c) __builtin_amdgcn_mfma_f32_16x16x32_bf16((a), (b), (c), 0, 0, 0)

// f32 -> bf16 round-to-nearest-even (bit trick)
__device__ __forceinline__ u16 f2b(float f) {
  union { float f; unsigned u; } x; x.f = f;
  unsigned r = x.u + 0x7fffu + ((x.u >> 16) & 1u);
  return (u16)(r >> 16);
}

__device__ __forceinline__ void gl_lds16(void* lds, const void* g) {
  __builtin_amdgcn_global_load_lds(
      (const __attribute__((address_space(1))) void*)g,
      (__attribute__((address_space(3))) void*)lds, 16, 0, 0);
}

// ---------------- f32 -> bf16 elementwise ----------------
__global__ __launch_bounds__(256) void cvt_kernel(const float* __restrict__ in,
                                                  u16* __restrict__ out, int n) {
  int i = (blockIdx.x * 256 + threadIdx.x) * 4;
  if (i >= n) return;
  f32x4 v = *(const f32x4*)(in + i);
  u16x4 o;
  o[0] = f2b(v[0]); o[1] = f2b(v[1]); o[2] = f2b(v[2]); o[3] = f2b(v[3]);
  *(u16x4*)(out + i) = o;
}

// ---------------- f32 [K][N] -> bf16 [N][K] transpose ----------------
__global__ __launch_bounds__(256) void cvt_t_kernel(const float* __restrict__ W,
                                                    u16* __restrict__ Wt, int K, int N) {
  __shared__ u16 t[32][33];
  const int n0 = blockIdx.x * 32, k0 = blockIdx.y * 32;
  const int tc = threadIdx.x & 31, tr = threadIdx.x >> 5; // tr: 0..7
#pragma unroll
  for (int i = 0; i < 4; i++)
    t[tr + i * 8][tc] = f2b(W[(size_t)(k0 + tr + i * 8) * N + n0 + tc]);
  __syncthreads();
#pragma unroll
  for (int i = 0; i < 4; i++)
    Wt[(size_t)(n0 + tr + i * 8) * K + k0 + tc] = t[tc][tr + i * 8];
}

// ---------------- shared GEMM body: C[M=4096][N] = A[4096][2048] @ Bt[N][2048]^T + bias ----------------
template <bool OUT_BF16>
__device__ __forceinline__ void gemm_body(const u16* __restrict__ A, const u16* __restrict__ Bt,
                                          const float* __restrict__ bias, void* __restrict__ C,
                                          const int N, const int n0, const int m0, const float scale) {
  __shared__ __align__(16) u16 As[128 * 32];
  __shared__ __align__(16) u16 Bs[128 * 32];
  const int lane = threadIdx.x & 63, wv = threadIdx.x >> 6;
  const int l15 = lane & 15, lg = lane >> 4;
  const int wm = wv >> 1, wn = wv & 1;
  const int rowQ = lane >> 2;
  const int g = lane & 3;

  f32x4 acc[4][4] = {};

  for (int k0 = 0; k0 < 2048; k0 += 32) {
#pragma unroll
    for (int c = 0; c < 2; c++) {
      const int cc = c * 4 + wv;
      const int row = cc * 16 + rowQ;
      const int gs = g ^ ((row >> 1) & 3);
      gl_lds16(&As[cc * 512], A + (((size_t)(m0 + row)) << 11) + k0 + gs * 8);
      gl_lds16(&Bs[cc * 512], Bt + (((size_t)(n0 + row)) << 11) + k0 + gs * 8);
    }
    __syncthreads();
    bf16x8 af[4], bfr[4];
#pragma unroll
    for (int t = 0; t < 4; t++) {
      const int ra = wm * 64 + t * 16 + l15;
      af[t] = *(const bf16x8*)&As[ra * 32 + ((lg ^ ((ra >> 1) & 3)) << 3)];
      const int rb = wn * 64 + t * 16 + l15;
      bfr[t] = *(const bf16x8*)&Bs[rb * 32 + ((lg ^ ((rb >> 1) & 3)) << 3)];
    }
#pragma unroll
    for (int mt = 0; mt < 4; mt++)
#pragma unroll
      for (int nt = 0; nt < 4; nt++)
        acc[mt][nt] = MFMA(af[mt], bfr[nt], acc[mt][nt]);
    __syncthreads();
  }

#pragma unroll
  for (int nt = 0; nt < 4; nt++) {
    const int col = n0 + wn * 64 + nt * 16 + l15;
    const float bc = bias[col];
#pragma unroll
    for (int mt = 0; mt < 4; mt++) {
#pragma unroll
      for (int r = 0; r < 4; r++) {
        const int row = m0 + wm * 64 + mt * 16 + lg * 4 + r;
        const float v = (acc[mt][nt][r] + bc) * scale;
        if (OUT_BF16) ((u16*)C)[(size_t)row * N + col] = f2b(v);
        else          ((float*)C)[(size_t)row * N + col] = v;
      }
    }
  }
}

// Fused QKV projection. Q is pre-scaled by (1/sqrt(64)) * log2(e) so attention uses exp2.
__global__ __launch_bounds__(256) void qkv_gemm_kernel(
    const u16* __restrict__ xb,
    const u16* __restrict__ Wqt, const u16* __restrict__ Wkt, const u16* __restrict__ Wvt,
    const float* __restrict__ bq, const float* __restrict__ bk, const float* __restrict__ bv,
    u16* __restrict__ Qb, u16* __restrict__ Kb, u16* __restrict__ Vb) {
  const int nb = blockIdx.x;
  const u16* Bt; const float* bias; u16* out; int N, n0; float scale;
  if (nb < 16)      { Bt = Wqt; bias = bq; out = Qb; N = 2048; n0 = nb * 128;        scale = 0.125f * 1.44269504f; }
  else if (nb < 20) { Bt = Wkt; bias = bk; out = Kb; N = 512;  n0 = (nb - 16) * 128; scale = 1.0f; }
  else              { Bt = Wvt; bias = bv; out = Vb; N = 512;  n0 = (nb - 20) * 128; scale = 1.0f; }
  gemm_body<true>(xb, Bt, bias, out, N, n0, blockIdx.y * 128, scale);
}

__global__ __launch_bounds__(256) void oproj_kernel(const u16* __restrict__ Ab,
                                                    const u16* __restrict__ Wot,
                                                    const float* __restrict__ bo,
                                                    float* __restrict__ out) {
  gemm_body<false>(Ab, Wot, bo, out, 2048, blockIdx.x * 128, blockIdx.y * 128, 1.0f);
}

// ---------------- causal GQA flash attention ----------------
// grid = (16 qtile-pairs, KV_HEAD=8, B=2); block = 512 (8 waves = 4 q-heads x 2 q-halves of 32).
// Each block processes q-tiles {p, 31-p} -> 33 KV-iterations, perfectly balanced.
// K/V tiles (64 kv x 64 d) double-buffered in LDS, shared by all 4 heads of the group.
__global__ __launch_bounds__(512) void attn_kernel(const u16* __restrict__ Qb,
                                                   const u16* __restrict__ Kb,
                                                   const u16* __restrict__ Vb,
                                                   u16* __restrict__ Ab) {
  const int pr = blockIdx.x, kh = blockIdx.y, b = blockIdx.z;
  const int tid = threadIdx.x;
  const int lane = tid & 63, wv = tid >> 6;
  const int hh = wv & 3, qh = wv >> 2;
  const int h = kh * 4 + hh;
  const int l15 = lane & 15, lg = lane >> 4;

  // K: element K[kv][d] at Ks[buf][kv*64 + (d ^ ((kv&7)<<3))]  (T2 swizzle, linear gl_lds dest,
  //    inverse-swizzled global source). V: element V[kv][d] at Vt[buf][d*64 + (kv ^ ((d&7)<<3))].
  __shared__ __align__(16) u16 Ks[2][64 * 64];
  __shared__ __align__(16) u16 Vt[2][64 * 64];
  __shared__ __align__(16) u16 Ps[8][32 * 72];   // per-wave P [32 q][64 kv], +8 pad

  const int skv = tid >> 3;      // kv row staged by this thread (0..63)
  const int sc8 = tid & 7;       // 16B chunk index / d0-block
  const int sd0 = sc8 * 8;

  const u16* Kbase = Kb + (size_t)(b * 2048) * 512 + kh * 64;
  const u16* Vbase = Vb + (size_t)(b * 2048) * 512 + kh * 64;
  u16* Pw = Ps[wv];

  for (int sel = 0; sel < 2; sel++) {
    const int qt = sel ? 31 - pr : pr;
    const int q0 = qt * 64;

    // Q fragments: 32 rows (2 x 16), d split in 2 ks-halves
    bf16x8 qf[2][2];
    {
      const u16* qp = Qb + (size_t)(b * 2048 + q0 + qh * 32 + l15) * 2048 + h * 64 + lg * 8;
      qf[0][0] = *(const bf16x8*)(qp);
      qf[0][1] = *(const bf16x8*)(qp + 32);
      qf[1][0] = *(const bf16x8*)(qp + 16 * 2048);
      qf[1][1] = *(const bf16x8*)(qp + 16 * 2048 + 32);
    }
    f32x4 o[2][4] = {};
    float mrow[2][4], srow[2][4];
#pragma unroll
    for (int qb = 0; qb < 2; qb++)
#pragma unroll
      for (int r = 0; r < 4; r++) { mrow[qb][r] = -1e30f; srow[qb][r] = 0.f; }

    __syncthreads();   // previous tile's LDS readers are done
    int cur = 0;
    {  // prologue: stage tile 0 into buf 0
      gl_lds16(&Ks[0][wv * 512], Kbase + ((size_t)skv << 9) + ((sc8 ^ (skv & 7)) << 3));
      u16x8 vr = *(const u16x8*)(Vbase + ((size_t)skv << 9) + sd0);
#pragma unroll
      for (int j = 0; j < 8; j++) {
        const int jj = (j + sc8) & 7;      // rotate so concurrent lanes hit different d&7
        const int d = sd0 + jj;
        Vt[0][d * 64 + (skv ^ ((d & 7) << 3))] = vr[jj];
      }
    }
    for (int it = 0; it <= qt; ++it) {
      __syncthreads();   // buf[cur] fully staged (drains vmcnt+lgkm per wave)
      const bool pre = (it < qt);
      u16x8 vnx;
      if (pre) {  // issue next tile's loads early; V LDS-write deferred past compute
        const size_t roff = (size_t)((it + 1) * 64 + skv) << 9;
        gl_lds16(&Ks[cur ^ 1][wv * 512], Kbase + roff + ((sc8 ^ (skv & 7)) << 3));
        vnx = *(const u16x8*)(Vbase + roff + sd0);
      }
      // S = Q K^T
      f32x4 sc[2][4] = {};
#pragma unroll
      for (int kt = 0; kt < 4; kt++) {
        const int krow = kt * 16 + l15;
#pragma unroll
        for (int ks = 0; ks < 2; ks++) {
          bf16x8 kf = *(const bf16x8*)&Ks[cur][krow * 64 + ((ks * 32 + lg * 8) ^ ((krow & 7) << 3))];
          sc[0][kt] = MFMA(qf[0][ks], kf, sc[0][kt]);
          sc[1][kt] = MFMA(qf[1][ks], kf, sc[1][kt]);
        }
      }
      if (it == qt) {  // causal mask on diagonal tile
#pragma unroll
        for (int qb = 0; qb < 2; qb++)
#pragma unroll
          for (int kt = 0; kt < 4; kt++)
#pragma unroll
            for (int r = 0; r < 4; r++) {
              const int q = qh * 32 + qb * 16 + lg * 4 + r;
              const int kv = kt * 16 + l15;
              if (kv > q) sc[qb][kt][r] = -1e30f;
            }
      }
      float tmax[2][4];
#pragma unroll
      for (int qb = 0; qb < 2; qb++)
#pragma unroll
        for (int r = 0; r < 4; r++)
          tmax[qb][r] = fmaxf(fmaxf(sc[qb][0][r], sc[qb][1][r]), fmaxf(sc[qb][2][r], sc[qb][3][r]));
#pragma unroll
      for (int m = 1; m < 16; m <<= 1)
#pragma unroll
        for (int qb = 0; qb < 2; qb++)
#pragma unroll
          for (int r = 0; r < 4; r++)
            tmax[qb][r] = fmaxf(tmax[qb][r], __shfl_xor(tmax[qb][r], m));
      float scl[2][4];
#pragma unroll
      for (int qb = 0; qb < 2; qb++)
#pragma unroll
        for (int r = 0; r < 4; r++) {
          const float mnew = fmaxf(mrow[qb][r], tmax[qb][r]);
          scl[qb][r] = exp2f(mrow[qb][r] - mnew);
          mrow[qb][r] = mnew;
        }
      float psum[2][4] = {};
#pragma unroll
      for (int qb = 0; qb < 2; qb++)
#pragma unroll
        for (int kt = 0; kt < 4; kt++)
#pragma unroll
          for (int r = 0; r < 4; r++) {
            const float pv = exp2f(sc[qb][kt][r] - mrow[qb][r]);
            psum[qb][r] += pv;
            Pw[(qb * 16 + lg * 4 + r) * 72 + kt * 16 + l15] = f2b(pv);
          }
#pragma unroll
      for (int m = 1; m < 16; m <<= 1)
#pragma unroll
        for (int qb = 0; qb < 2; qb++)
#pragma unroll
          for (int r = 0; r < 4; r++)
            psum[qb][r] += __shfl_xor(psum[qb][r], m);
#pragma unroll
      for (int qb = 0; qb < 2; qb++)
#pragma unroll
        for (int r = 0; r < 4; r++)
          srow[qb][r] = srow[qb][r] * scl[qb][r] + psum[qb][r];
#pragma unroll
      for (int qb = 0; qb < 2; qb++)
#pragma unroll
        for (int dt = 0; dt < 4; dt++)
#pragma unroll
          for (int r = 0; r < 4; r++)
            o[qb][dt][r] *= scl[qb][r];
      // O += P V
#pragma unroll
      for (int ks = 0; ks < 2; ks++) {
        bf16x8 pf0 = *(const bf16x8*)&Pw[l15 * 72 + ks * 32 + lg * 8];
        bf16x8 pf1 = *(const bf16x8*)&Pw[(16 + l15) * 72 + ks * 32 + lg * 8];
#pragma unroll
        for (int dt = 0; dt < 4; dt++) {
          const int drow = dt * 16 + l15;
          bf16x8 vf = *(const bf16x8*)&Vt[cur][drow * 64 + ((ks * 32 + lg * 8) ^ ((drow & 7) << 3))];
          o[0][dt] = MFMA(pf0, vf, o[0][dt]);
          o[1][dt] = MFMA(pf1, vf, o[1][dt]);
        }
      }
      if (pre) {  // deferred V write into next buffer (HBM latency hidden under compute)
#pragma unroll
        for (int j = 0; j < 8; j++) {
          const int jj = (j + sc8) & 7;
          const int d = sd0 + jj;
          Vt[cur ^ 1][d * 64 + (skv ^ ((d & 7) << 3))] = vnx[jj];
        }
      }
      cur ^= 1;
    }
    // epilogue
#pragma unroll
    for (int qb = 0; qb < 2; qb++) {
      float inv[4];
#pragma unroll
      for (int r = 0; r < 4; r++) inv[r] = 1.0f / srow[qb][r];
#pragma unroll
      for (int dt = 0; dt < 4; dt++)
#pragma unroll
        for (int r = 0; r < 4; r++) {
          const int q = q0 + qh * 32 + qb * 16 + lg * 4 + r;
          Ab[(size_t)(b * 2048 + q) * 2048 + h * 64 + dt * 16 + l15] = f2b(o[qb][dt][r] * inv[r]);
        }
    }
  }
}

extern "C" void kernel_launch(void* const* d_in, const int* in_sizes, int n_in,
                              void* d_out, int out_size, void* d_ws, size_t ws_size,
                              hipStream_t stream) {
  const float* x  = (const float*)d_in[0];
  const float* Wq = (const float*)d_in[1];
  const float* bq = (const float*)d_in[2];
  const float* Wk = (const float*)d_in[3];
  const float* bk = (const float*)d_in[4];
  const float* Wv = (const float*)d_in[5];
  const float* bv = (const float*)d_in[6];
  const float* Wo = (const float*)d_in[7];
  const float* bo = (const float*)d_in[8];

  char* ws = (char*)d_ws;
  u16* xb  = (u16*)(ws + 0);          // 4096*2048 bf16 = 16 MiB
  u16* Ab  = (u16*)(ws + 0);          // aliases xb (xb dead after QKV gemm)
  u16* Qb  = (u16*)(ws + 16777216);   // 4096*2048
  u16* Kb  = (u16*)(ws + 33554432);   // 4096*512
  u16* Vb  = (u16*)(ws + 37748736);   // 4096*512
  u16* Wqt = (u16*)(ws + 41943040);   // 2048*2048
  u16* Wkt = (u16*)(ws + 50331648);   // 512*2048
  u16* Wvt = (u16*)(ws + 52428800);   // 512*2048
  u16* Wot = (u16*)(ws + 54525952);   // 2048*2048

  cvt_kernel<<<8192, 256, 0, stream>>>(x, xb, 2 * 2048 * 2048);
  cvt_t_kernel<<<dim3(64, 64), 256, 0, stream>>>(Wq, Wqt, 2048, 2048);
  cvt_t_kernel<<<dim3(16, 64), 256, 0, stream>>>(Wk, Wkt, 2048, 512);
  cvt_t_kernel<<<dim3(16, 64), 256, 0, stream>>>(Wv, Wvt, 2048, 512);
  cvt_t_kernel<<<dim3(64, 64), 256, 0, stream>>>(Wo, Wot, 2048, 2048);

  qkv_gemm_kernel<<<dim3(24, 32), 256, 0, stream>>>(xb, Wqt, Wkt, Wvt, bq, bk, bv, Qb, Kb, Vb);
  attn_kernel<<<dim3(16, 8, 2), 512, 0, stream>>>(Qb, Kb, Vb, Ab);
  oproj_kernel<<<dim3(16, 32), 256, 0, stream>>>(Ab, Wot, bo, (float*)d_out);
}

// Round 3
// 248.066 us; speedup vs baseline: 1.9720x; 1.2328x over previous
//
#include <hip/hip_runtime.h>
#include <hip/hip_bf16.h>

typedef unsigned short u16;
typedef __attribute__((ext_vector_type(8)))  __bf16 bf16x8;
typedef __attribute__((ext_vector_type(8)))  unsigned short u16x8;
typedef __attribute__((ext_vector_type(4)))  unsigned short u16x4;
typedef __attribute__((ext_vector_type(4)))  float f32x4;

#define MFMA(a, b, c) __builtin_amdgcn_mfma_f32_16x16x32_bf16((a), (b), (c), 0, 0, 0)

// f32 -> bf16 round-to-nearest-even (bit trick)
__device__ __forceinline__ u16 f2b(float f) {
  union { float f; unsigned u; } x; x.f = f;
  unsigned r = x.u + 0x7fffu + ((x.u >> 16) & 1u);
  return (u16)(r >> 16);
}

__device__ __forceinline__ void gl_lds16(void* lds, const void* g) {
  __builtin_amdgcn_global_load_lds(
      (const __attribute__((address_space(1))) void*)g,
      (__attribute__((address_space(3))) void*)lds, 16, 0, 0);
}

// ---------------- f32 -> bf16 elementwise ----------------
__global__ __launch_bounds__(256) void cvt_kernel(const float* __restrict__ in,
                                                  u16* __restrict__ out, int n) {
  int i = (blockIdx.x * 256 + threadIdx.x) * 4;
  if (i >= n) return;
  f32x4 v = *(const f32x4*)(in + i);
  u16x4 o;
  o[0] = f2b(v[0]); o[1] = f2b(v[1]); o[2] = f2b(v[2]); o[3] = f2b(v[3]);
  *(u16x4*)(out + i) = o;
}

// ---------------- f32 [K][N] -> bf16 [N][K] transpose ----------------
__global__ __launch_bounds__(256) void cvt_t_kernel(const float* __restrict__ W,
                                                    u16* __restrict__ Wt, int K, int N) {
  __shared__ u16 t[32][33];
  const int n0 = blockIdx.x * 32, k0 = blockIdx.y * 32;
  const int tc = threadIdx.x & 31, tr = threadIdx.x >> 5; // tr: 0..7
#pragma unroll
  for (int i = 0; i < 4; i++)
    t[tr + i * 8][tc] = f2b(W[(size_t)(k0 + tr + i * 8) * N + n0 + tc]);
  __syncthreads();
#pragma unroll
  for (int i = 0; i < 4; i++)
    Wt[(size_t)(n0 + tr + i * 8) * K + k0 + tc] = t[tc][tr + i * 8];
}

// ---------------- shared GEMM body: C[M=4096][N] = A[4096][2048] @ Bt[N][2048]^T + bias ----------------
template <bool OUT_BF16>
__device__ __forceinline__ void gemm_body(const u16* __restrict__ A, const u16* __restrict__ Bt,
                                          const float* __restrict__ bias, void* __restrict__ C,
                                          const int N, const int n0, const int m0, const float scale) {
  __shared__ __align__(16) u16 As[128 * 32];
  __shared__ __align__(16) u16 Bs[128 * 32];
  const int lane = threadIdx.x & 63, wv = threadIdx.x >> 6;
  const int l15 = lane & 15, lg = lane >> 4;
  const int wm = wv >> 1, wn = wv & 1;
  const int rowQ = lane >> 2;
  const int g = lane & 3;

  f32x4 acc[4][4] = {};

  for (int k0 = 0; k0 < 2048; k0 += 32) {
#pragma unroll
    for (int c = 0; c < 2; c++) {
      const int cc = c * 4 + wv;
      const int row = cc * 16 + rowQ;
      const int gs = g ^ ((row >> 1) & 3);
      gl_lds16(&As[cc * 512], A + (((size_t)(m0 + row)) << 11) + k0 + gs * 8);
      gl_lds16(&Bs[cc * 512], Bt + (((size_t)(n0 + row)) << 11) + k0 + gs * 8);
    }
    __syncthreads();
    bf16x8 af[4], bfr[4];
#pragma unroll
    for (int t = 0; t < 4; t++) {
      const int ra = wm * 64 + t * 16 + l15;
      af[t] = *(const bf16x8*)&As[ra * 32 + ((lg ^ ((ra >> 1) & 3)) << 3)];
      const int rb = wn * 64 + t * 16 + l15;
      bfr[t] = *(const bf16x8*)&Bs[rb * 32 + ((lg ^ ((rb >> 1) & 3)) << 3)];
    }
#pragma unroll
    for (int mt = 0; mt < 4; mt++)
#pragma unroll
      for (int nt = 0; nt < 4; nt++)
        acc[mt][nt] = MFMA(af[mt], bfr[nt], acc[mt][nt]);
    __syncthreads();
  }

#pragma unroll
  for (int nt = 0; nt < 4; nt++) {
    const int col = n0 + wn * 64 + nt * 16 + l15;
    const float bc = bias[col];
#pragma unroll
    for (int mt = 0; mt < 4; mt++) {
#pragma unroll
      for (int r = 0; r < 4; r++) {
        const int row = m0 + wm * 64 + mt * 16 + lg * 4 + r;
        const float v = (acc[mt][nt][r] + bc) * scale;
        if (OUT_BF16) ((u16*)C)[(size_t)row * N + col] = f2b(v);
        else          ((float*)C)[(size_t)row * N + col] = v;
      }
    }
  }
}

// Fused QKV projection. Q is pre-scaled by (1/sqrt(64)) * log2(e) so attention uses exp2.
__global__ __launch_bounds__(256) void qkv_gemm_kernel(
    const u16* __restrict__ xb,
    const u16* __restrict__ Wqt, const u16* __restrict__ Wkt, const u16* __restrict__ Wvt,
    const float* __restrict__ bq, const float* __restrict__ bk, const float* __restrict__ bv,
    u16* __restrict__ Qb, u16* __restrict__ Kb, u16* __restrict__ Vb) {
  const int nb = blockIdx.x;
  const u16* Bt; const float* bias; u16* out; int N, n0; float scale;
  if (nb < 16)      { Bt = Wqt; bias = bq; out = Qb; N = 2048; n0 = nb * 128;        scale = 0.125f * 1.44269504f; }
  else if (nb < 20) { Bt = Wkt; bias = bk; out = Kb; N = 512;  n0 = (nb - 16) * 128; scale = 1.0f; }
  else              { Bt = Wvt; bias = bv; out = Vb; N = 512;  n0 = (nb - 20) * 128; scale = 1.0f; }
  gemm_body<true>(xb, Bt, bias, out, N, n0, blockIdx.y * 128, scale);
}

__global__ __launch_bounds__(256) void oproj_kernel(const u16* __restrict__ Ab,
                                                    const u16* __restrict__ Wot,
                                                    const float* __restrict__ bo,
                                                    float* __restrict__ out) {
  gemm_body<false>(Ab, Wot, bo, out, 2048, blockIdx.x * 128, blockIdx.y * 128, 1.0f);
}

// ---------------- causal GQA flash attention ----------------
// grid = (16 qtile-pairs, KV_HEAD=8, B=2); block = 1024 (16 waves = 4 heads x 4 q-quarters of 16).
// Each block processes q-tiles {p, 31-p} -> 33 KV-iterations, perfectly balanced.
// K staged by waves 0-7 via global_load_lds; V reg-staged by waves 8-15 (issue-early/write-late).
// Row-sum via MFMA with all-ones B (no shuffle reduce); defer-max (THR=8) skips most rescales.
__global__ __launch_bounds__(1024) void attn_kernel(const u16* __restrict__ Qb,
                                                    const u16* __restrict__ Kb,
                                                    const u16* __restrict__ Vb,
                                                    u16* __restrict__ Ab) {
  const int pr = blockIdx.x, kh = blockIdx.y, b = blockIdx.z;
  const int tid = threadIdx.x;
  const int lane = tid & 63, wv = tid >> 6;
  const int hh = wv & 3, qq = wv >> 2;      // head-in-group, q-quarter
  const int h = kh * 4 + hh;
  const int l15 = lane & 15, lg = lane >> 4;

  // K[kv][d] at Ks[buf][kv*64 + (d ^ ((kv&7)<<3))]; V[kv][d] at Vt[buf][d*64 + (kv ^ ((d&7)<<3))]
  __shared__ __align__(16) u16 Ks[2][64 * 64];
  __shared__ __align__(16) u16 Vt[2][64 * 64];
  __shared__ __align__(16) u16 Ps[16][16 * 72];   // per-wave P [16 q][64 kv], +8 pad

  const int skv = (tid & 511) >> 3;  // kv row staged (0..63), same for K- and V-role waves
  const int sc8 = tid & 7;
  const int sd0 = sc8 * 8;
  const bool kRole = (wv < 8);

  const u16* Kbase = Kb + (size_t)(b * 2048) * 512 + kh * 64;
  const u16* Vbase = Vb + (size_t)(b * 2048) * 512 + kh * 64;
  u16* Pw = Ps[wv];

  __bf16 one1 = (__bf16)1.0f;
  bf16x8 ones = {one1, one1, one1, one1, one1, one1, one1, one1};

  for (int sel = 0; sel < 2; sel++) {
    const int qt = sel ? 31 - pr : pr;
    const int q0 = qt * 64;

    bf16x8 qf[2];
    {
      const u16* qp = Qb + (size_t)(b * 2048 + q0 + qq * 16 + l15) * 2048 + h * 64 + lg * 8;
      qf[0] = *(const bf16x8*)(qp);
      qf[1] = *(const bf16x8*)(qp + 32);
    }
    f32x4 o[4] = {};
    f32x4 os = {};                       // row-sum accumulator (ones-column)
    float mrow[4] = {-1e30f, -1e30f, -1e30f, -1e30f};

    __syncthreads();   // previous tile's LDS readers are done
    int cur = 0;
    if (kRole) {
      gl_lds16(&Ks[0][wv * 512], Kbase + ((size_t)skv << 9) + ((sc8 ^ (skv & 7)) << 3));
    } else {
      u16x8 vr = *(const u16x8*)(Vbase + ((size_t)skv << 9) + sd0);
#pragma unroll
      for (int j = 0; j < 8; j++) {
        const int jj = (j + sc8) & 7;
        const int d = sd0 + jj;
        Vt[0][d * 64 + (skv ^ ((d & 7) << 3))] = vr[jj];
      }
    }
    for (int it = 0; it <= qt; ++it) {
      __syncthreads();   // buf[cur] fully staged
      const bool pre = (it < qt);
      u16x8 vnx;
      if (pre) {  // issue next tile's loads early; V LDS-write deferred past compute
        const size_t roff = (size_t)((it + 1) * 64 + skv) << 9;
        if (kRole) gl_lds16(&Ks[cur ^ 1][wv * 512], Kbase + roff + ((sc8 ^ (skv & 7)) << 3));
        else       vnx = *(const u16x8*)(Vbase + roff + sd0);
      }
      // S = Q K^T
      f32x4 sc[4] = {};
#pragma unroll
      for (int kt = 0; kt < 4; kt++) {
        const int krow = kt * 16 + l15;
#pragma unroll
        for (int ks = 0; ks < 2; ks++) {
          bf16x8 kf = *(const bf16x8*)&Ks[cur][krow * 64 + ((ks * 32 + lg * 8) ^ ((krow & 7) << 3))];
          sc[kt] = MFMA(qf[ks], kf, sc[kt]);
        }
      }
      if (it == qt) {  // causal mask on diagonal tile
#pragma unroll
        for (int kt = 0; kt < 4; kt++)
#pragma unroll
          for (int r = 0; r < 4; r++) {
            const int q = qq * 16 + lg * 4 + r;
            const int kv = kt * 16 + l15;
            if (kv > q) sc[kt][r] = -1e30f;
          }
      }
      // row max over kv: 3 fmax + 4-stage shuffle over l15
      float tmax[4];
#pragma unroll
      for (int r = 0; r < 4; r++)
        tmax[r] = fmaxf(fmaxf(sc[0][r], sc[1][r]), fmaxf(sc[2][r], sc[3][r]));
#pragma unroll
      for (int m = 1; m < 16; m <<= 1)
#pragma unroll
        for (int r = 0; r < 4; r++)
          tmax[r] = fmaxf(tmax[r], __shfl_xor(tmax[r], m));
      // defer-max (T13): rescale only if max grew by > 8 (in log2 units)
      int need = 0;
#pragma unroll
      for (int r = 0; r < 4; r++) need |= (tmax[r] > mrow[r] + 8.0f) ? 1 : 0;
      if (__any(need)) {
#pragma unroll
        for (int r = 0; r < 4; r++) {
          const float mnew = fmaxf(mrow[r], tmax[r]);
          const float scl = __builtin_amdgcn_exp2f(mrow[r] - mnew);
          mrow[r] = mnew;
          os[r] *= scl;
#pragma unroll
          for (int dt = 0; dt < 4; dt++) o[dt][r] *= scl;
        }
      }
      // P = exp2(S - m), native bf16 cvt (v_cvt_pk), store to per-wave LDS
#pragma unroll
      for (int kt = 0; kt < 4; kt++)
#pragma unroll
        for (int r = 0; r < 4; r++) {
          const float pv = __builtin_amdgcn_exp2f(sc[kt][r] - mrow[r]);
          const __bf16 pb = (__bf16)pv;
          Pw[(lg * 4 + r) * 72 + kt * 16 + l15] = __builtin_bit_cast(u16, pb);
        }
      // O += P V ; row-sum += P * ones (replaces shuffle reduce)
#pragma unroll
      for (int ks = 0; ks < 2; ks++) {
        bf16x8 pf = *(const bf16x8*)&Pw[l15 * 72 + ks * 32 + lg * 8];
        os = MFMA(pf, ones, os);
#pragma unroll
        for (int dt = 0; dt < 4; dt++) {
          const int drow = dt * 16 + l15;
          bf16x8 vf = *(const bf16x8*)&Vt[cur][drow * 64 + ((ks * 32 + lg * 8) ^ ((drow & 7) << 3))];
          o[dt] = MFMA(pf, vf, o[dt]);
        }
      }
      if (pre && !kRole) {  // deferred V write into next buffer
#pragma unroll
        for (int j = 0; j < 8; j++) {
          const int jj = (j + sc8) & 7;
          const int d = sd0 + jj;
          Vt[cur ^ 1][d * 64 + (skv ^ ((d & 7) << 3))] = vnx[jj];
        }
      }
      cur ^= 1;
    }
    // epilogue
    float inv[4];
#pragma unroll
    for (int r = 0; r < 4; r++) inv[r] = 1.0f / os[r];
#pragma unroll
    for (int dt = 0; dt < 4; dt++)
#pragma unroll
      for (int r = 0; r < 4; r++) {
        const int q = q0 + qq * 16 + lg * 4 + r;
        Ab[(size_t)(b * 2048 + q) * 2048 + h * 64 + dt * 16 + l15] = f2b(o[dt][r] * inv[r]);
      }
  }
}

extern "C" void kernel_launch(void* const* d_in, const int* in_sizes, int n_in,
                              void* d_out, int out_size, void* d_ws, size_t ws_size,
                              hipStream_t stream) {
  const float* x  = (const float*)d_in[0];
  const float* Wq = (const float*)d_in[1];
  const float* bq = (const float*)d_in[2];
  const float* Wk = (const float*)d_in[3];
  const float* bk = (const float*)d_in[4];
  const float* Wv = (const float*)d_in[5];
  const float* bv = (const float*)d_in[6];
  const float* Wo = (const float*)d_in[7];
  const float* bo = (const float*)d_in[8];

  char* ws = (char*)d_ws;
  u16* xb  = (u16*)(ws + 0);          // 4096*2048 bf16 = 16 MiB
  u16* Ab  = (u16*)(ws + 0);          // aliases xb (xb dead after QKV gemm)
  u16* Qb  = (u16*)(ws + 16777216);   // 4096*2048
  u16* Kb  = (u16*)(ws + 33554432);   // 4096*512
  u16* Vb  = (u16*)(ws + 37748736);   // 4096*512
  u16* Wqt = (u16*)(ws + 41943040);   // 2048*2048
  u16* Wkt = (u16*)(ws + 50331648);   // 512*2048
  u16* Wvt = (u16*)(ws + 52428800);   // 512*2048
  u16* Wot = (u16*)(ws + 54525952);   // 2048*2048

  cvt_kernel<<<8192, 256, 0, stream>>>(x, xb, 2 * 2048 * 2048);
  cvt_t_kernel<<<dim3(64, 64), 256, 0, stream>>>(Wq, Wqt, 2048, 2048);
  cvt_t_kernel<<<dim3(16, 64), 256, 0, stream>>>(Wk, Wkt, 2048, 512);
  cvt_t_kernel<<<dim3(16, 64), 256, 0, stream>>>(Wv, Wvt, 2048, 512);
  cvt_t_kernel<<<dim3(64, 64), 256, 0, stream>>>(Wo, Wot, 2048, 2048);

  qkv_gemm_kernel<<<dim3(24, 32), 256, 0, stream>>>(xb, Wqt, Wkt, Wvt, bq, bk, bv, Qb, Kb, Vb);
  attn_kernel<<<dim3(16, 8, 2), 1024, 0, stream>>>(Qb, Kb, Vb, Ab);
  oproj_kernel<<<dim3(16, 32), 256, 0, stream>>>(Ab, Wot, bo, (float*)d_out);
}